// Round 1
// baseline (588.573 us; speedup 1.0000x reference)
//
#include <hip/hip_runtime.h>
#include <hip/hip_bf16.h>

typedef __attribute__((ext_vector_type(8))) short bf16x8;
typedef __attribute__((ext_vector_type(4))) float f32x4;

// ---------------- fp32 -> bf16 conversion (8 elems/thread) ----------------
struct bf16x8_s { __hip_bfloat16 h[8]; };

__global__ void cvt_kernel(const float* __restrict__ in,
                           __hip_bfloat16* __restrict__ out, int n8) {
  int i = blockIdx.x * blockDim.x + threadIdx.x;
  if (i >= n8) return;
  const float4* p = reinterpret_cast<const float4*>(in) + (size_t)i * 2;
  float4 a = p[0], b = p[1];
  bf16x8_s o;
  o.h[0] = __float2bfloat16(a.x); o.h[1] = __float2bfloat16(a.y);
  o.h[2] = __float2bfloat16(a.z); o.h[3] = __float2bfloat16(a.w);
  o.h[4] = __float2bfloat16(b.x); o.h[5] = __float2bfloat16(b.y);
  o.h[6] = __float2bfloat16(b.z); o.h[7] = __float2bfloat16(b.w);
  *reinterpret_cast<bf16x8_s*>(out + (size_t)i * 8) = o;
}

// ---------------- bf16 GEMM: C[M,N] = A[M,K] @ W[N,K]^T + bias -------------
// MODE 0: bf16 row-major [M][N]
// MODE 1: bf16 V-transpose epilogue: out[((b*16+h)*64+d)*2048 + t]
// MODE 2: fp32 row-major [M][N]
template <int MODE>
__global__ __launch_bounds__(256) void gemm_bt(
    const __hip_bfloat16* __restrict__ A, const __hip_bfloat16* __restrict__ W,
    const float* __restrict__ bias, void* __restrict__ Cout, int M, int N,
    int K) {
  constexpr int BM = 128, BN = 128, BK = 64;
  __shared__ __hip_bfloat16 As[BM][BK];
  __shared__ __hip_bfloat16 Ws[BN][BK];
  const int tid = threadIdx.x;
  const int lane = tid & 63;
  const int lrow = lane & 15;
  const int lhi = lane >> 4;
  const int lk8 = lhi * 8;
  const int wid = tid >> 6;
  const int wm = wid >> 1, wn = wid & 1;
  const int row0 = blockIdx.x * BM, col0 = blockIdx.y * BN;

  f32x4 acc[4][4] = {};

  for (int k0 = 0; k0 < K; k0 += BK) {
#pragma unroll
    for (int c = 0; c < 4; ++c) {
      const int e = (c * 256 + tid) * 8;           // this lane's elem offset
      const int eb = (c * 256 + (tid & 192)) * 8;  // wave-uniform LDS base
      const int r = e >> 6, cc = e & 63;
      __builtin_amdgcn_global_load_lds(
          (const __attribute__((address_space(1))) void*)(A + (size_t)(row0 + r) * K + k0 + cc),
          (__attribute__((address_space(3))) void*)(&As[0][0] + eb), 16, 0, 0);
    }
#pragma unroll
    for (int c = 0; c < 4; ++c) {
      const int e = (c * 256 + tid) * 8;
      const int eb = (c * 256 + (tid & 192)) * 8;
      const int r = e >> 6, cc = e & 63;
      __builtin_amdgcn_global_load_lds(
          (const __attribute__((address_space(1))) void*)(W + (size_t)(col0 + r) * K + k0 + cc),
          (__attribute__((address_space(3))) void*)(&Ws[0][0] + eb), 16, 0, 0);
    }
    __syncthreads();
#pragma unroll
    for (int kk = 0; kk < 2; ++kk) {
      bf16x8 af[4], bfr[4];
#pragma unroll
      for (int m = 0; m < 4; ++m)
        af[m] = *reinterpret_cast<const bf16x8*>(&As[wm * 64 + m * 16 + lrow][kk * 32 + lk8]);
#pragma unroll
      for (int n = 0; n < 4; ++n)
        bfr[n] = *reinterpret_cast<const bf16x8*>(&Ws[wn * 64 + n * 16 + lrow][kk * 32 + lk8]);
#pragma unroll
      for (int m = 0; m < 4; ++m)
#pragma unroll
        for (int n = 0; n < 4; ++n)
          acc[m][n] = __builtin_amdgcn_mfma_f32_16x16x32_bf16(af[m], bfr[n], acc[m][n], 0, 0, 0);
    }
    __syncthreads();
  }

  float bv[4];
#pragma unroll
  for (int n = 0; n < 4; ++n) bv[n] = bias[col0 + wn * 64 + n * 16 + lrow];

#pragma unroll
  for (int m = 0; m < 4; ++m) {
#pragma unroll
    for (int n = 0; n < 4; ++n) {
#pragma unroll
      for (int i = 0; i < 4; ++i) {
        const int row = row0 + wm * 64 + m * 16 + lhi * 4 + i;
        const int col = col0 + wn * 64 + n * 16 + lrow;
        const float v = acc[m][n][i] + bv[n];
        if constexpr (MODE == 0) {
          ((__hip_bfloat16*)Cout)[(size_t)row * N + col] = __float2bfloat16(v);
        } else if constexpr (MODE == 1) {
          const int t = row & 2047, b = row >> 11;
          const size_t idx =
              ((size_t)((b * 16 + (col >> 6)) * 64 + (col & 63))) * 2048 + t;
          ((__hip_bfloat16*)Cout)[idx] = __float2bfloat16(v);
        } else {
          ((float*)Cout)[(size_t)row * N + col] = v;
        }
      }
    }
  }
}

// ---------------- flash attention -----------------------------------------
// Q,K: [B*T][C] bf16 (head h at cols h*64..h*64+63). Vt: [B*H*64][T] bf16.
// Y: [B*T][C] bf16. Grid (T/64, B*H), 256 thr = 4 waves; wave owns 16 q-rows.
__global__ __launch_bounds__(256) void attn_fwd(
    const __hip_bfloat16* __restrict__ Q, const __hip_bfloat16* __restrict__ Km,
    const __hip_bfloat16* __restrict__ Vt, __hip_bfloat16* __restrict__ Y) {
  constexpr int T = 2048, C = 1024, D = 64;
  const int tid = threadIdx.x;
  const int wid = tid >> 6;
  const int lane = tid & 63;
  const int lrow = lane & 15;
  const int lhi = lane >> 4;
  const int qt = blockIdx.x;
  const int bh = blockIdx.y;
  const int b = bh >> 4, h = bh & 15;
  const int q0 = qt * 64 + wid * 16;

  const __hip_bfloat16* Qb = Q + ((size_t)b * T) * C + h * D;
  const __hip_bfloat16* Kb = Km + ((size_t)b * T) * C + h * D;
  const __hip_bfloat16* Vb = Vt + (size_t)bh * D * T;

  __shared__ __hip_bfloat16 Plds[4][16][32];  // per-wave private 1 KB

  bf16x8 qf[2];
#pragma unroll
  for (int kk = 0; kk < 2; ++kk)
    qf[kk] = *reinterpret_cast<const bf16x8*>(Qb + (size_t)(q0 + lrow) * C + kk * 32 + lhi * 8);

  f32x4 o[4] = {};
  float m4[4], l4[4];
#pragma unroll
  for (int i = 0; i < 4; ++i) { m4[i] = -1e30f; l4[i] = 0.f; }

  const int kv_end = q0 + 16;
  for (int kv0 = 0; kv0 < kv_end; kv0 += 32) {
    // ---- S = (Q K^T) : two 16-col fragments
    f32x4 s[2] = {};
#pragma unroll
    for (int n = 0; n < 2; ++n)
#pragma unroll
      for (int kk = 0; kk < 2; ++kk) {
        bf16x8 kf = *reinterpret_cast<const bf16x8*>(
            Kb + (size_t)(kv0 + n * 16 + lrow) * C + kk * 32 + lhi * 8);
        s[n] = __builtin_amdgcn_mfma_f32_16x16x32_bf16(qf[kk], kf, s[n], 0, 0, 0);
      }
    // ---- scale + causal mask + online softmax (rows: q0+4*lhi+i, col: kv0+n*16+lrow)
    float p[2][4], nm[4];
#pragma unroll
    for (int i = 0; i < 4; ++i) {
      const int row = q0 + 4 * lhi + i;
      float v0 = (kv0 + lrow <= row) ? s[0][i] * 0.125f : -1e30f;
      float v1 = (kv0 + 16 + lrow <= row) ? s[1][i] * 0.125f : -1e30f;
      p[0][i] = v0; p[1][i] = v1;
      float mx = fmaxf(v0, v1);
      mx = fmaxf(mx, __shfl_xor(mx, 1, 16));
      mx = fmaxf(mx, __shfl_xor(mx, 2, 16));
      mx = fmaxf(mx, __shfl_xor(mx, 4, 16));
      mx = fmaxf(mx, __shfl_xor(mx, 8, 16));
      nm[i] = fmaxf(m4[i], mx);
    }
#pragma unroll
    for (int i = 0; i < 4; ++i) {
      const float a = __expf(m4[i] - nm[i]);
      m4[i] = nm[i];
      const float e0 = __expf(p[0][i] - nm[i]);
      const float e1 = __expf(p[1][i] - nm[i]);
      p[0][i] = e0; p[1][i] = e1;
      float sum = e0 + e1;
      sum += __shfl_xor(sum, 1, 16);
      sum += __shfl_xor(sum, 2, 16);
      sum += __shfl_xor(sum, 4, 16);
      sum += __shfl_xor(sum, 8, 16);
      l4[i] = l4[i] * a + sum;
#pragma unroll
      for (int f = 0; f < 4; ++f) o[f][i] *= a;
    }
    // ---- P (D-layout) -> LDS -> A-layout fragment
#pragma unroll
    for (int n = 0; n < 2; ++n)
#pragma unroll
      for (int i = 0; i < 4; ++i)
        Plds[wid][4 * lhi + i][n * 16 + lrow] = __float2bfloat16(p[n][i]);
    bf16x8 pf = *reinterpret_cast<const bf16x8*>(&Plds[wid][lrow][lhi * 8]);
    // ---- O += P V  (V^T rows are d, cols t -> contiguous 16B loads)
#pragma unroll
    for (int f = 0; f < 4; ++f) {
      bf16x8 vf = *reinterpret_cast<const bf16x8*>(
          Vb + (size_t)(f * 16 + lrow) * T + kv0 + lhi * 8);
      o[f] = __builtin_amdgcn_mfma_f32_16x16x32_bf16(pf, vf, o[f], 0, 0, 0);
    }
  }
  // ---- normalize + store
#pragma unroll
  for (int f = 0; f < 4; ++f)
#pragma unroll
    for (int i = 0; i < 4; ++i) {
      const int row = q0 + 4 * lhi + i;
      Y[((size_t)b * T + row) * C + h * D + f * 16 + lrow] =
          __float2bfloat16(o[f][i] / l4[i]);
    }
}

// ---------------- host launch ----------------------------------------------
extern "C" void kernel_launch(void* const* d_in, const int* in_sizes, int n_in,
                              void* d_out, int out_size, void* d_ws,
                              size_t ws_size, hipStream_t stream) {
  const float* x = (const float*)d_in[0];
  const float* Wq = (const float*)d_in[1];
  const float* bq = (const float*)d_in[2];
  const float* Wk = (const float*)d_in[3];
  const float* bk = (const float*)d_in[4];
  const float* Wv = (const float*)d_in[5];
  const float* bv = (const float*)d_in[6];
  const float* Wp = (const float*)d_in[7];
  const float* bp = (const float*)d_in[8];
  float* out = (float*)d_out;

  __hip_bfloat16* ws = (__hip_bfloat16*)d_ws;
  __hip_bfloat16* xb = ws;                   // 8388608
  __hip_bfloat16* wqb = xb + 8388608;        // 1048576
  __hip_bfloat16* wkb = wqb + 1048576;
  __hip_bfloat16* wvb = wkb + 1048576;
  __hip_bfloat16* wpb = wvb + 1048576;
  __hip_bfloat16* Qs = wpb + 1048576;        // 8388608
  __hip_bfloat16* Ks = Qs + 8388608;
  __hip_bfloat16* Vts = Ks + 8388608;        // V^T: [B*H*64][2048]
  __hip_bfloat16* Ys = Vts + 8388608;        // attn out [B*T][C]
  // total = 92,274,688 bytes of d_ws

  cvt_kernel<<<4096, 256, 0, stream>>>(x, xb, 1048576);
  cvt_kernel<<<512, 256, 0, stream>>>(Wq, wqb, 131072);
  cvt_kernel<<<512, 256, 0, stream>>>(Wk, wkb, 131072);
  cvt_kernel<<<512, 256, 0, stream>>>(Wv, wvb, 131072);
  cvt_kernel<<<512, 256, 0, stream>>>(Wp, wpb, 131072);

  dim3 g(8192 / 128, 1024 / 128);
  gemm_bt<0><<<g, 256, 0, stream>>>(xb, wqb, bq, Qs, 8192, 1024, 1024);
  gemm_bt<0><<<g, 256, 0, stream>>>(xb, wkb, bk, Ks, 8192, 1024, 1024);
  gemm_bt<1><<<g, 256, 0, stream>>>(xb, wvb, bv, Vts, 8192, 1024, 1024);

  attn_fwd<<<dim3(32, 64), 256, 0, stream>>>(Qs, Ks, Vts, Ys);

  gemm_bt<2><<<g, 256, 0, stream>>>(Ys, wpb, bp, out, 8192, 1024, 1024);
}

// Round 2
// 383.452 us; speedup vs baseline: 1.5349x; 1.5349x over previous
//
#include <hip/hip_runtime.h>
#include <hip/hip_bf16.h>

typedef __attribute__((ext_vector_type(8))) short bf16x8;
typedef __attribute__((ext_vector_type(4))) float f32x4;

// ---------------- fp32 -> bf16 conversion (8 elems/thread) ----------------
struct bf16x8_s { __hip_bfloat16 h[8]; };
struct bf16x4_s { __hip_bfloat16 h[4]; };

__global__ void cvt_kernel(const float* __restrict__ in,
                           __hip_bfloat16* __restrict__ out, int n8) {
  int i = blockIdx.x * blockDim.x + threadIdx.x;
  if (i >= n8) return;
  const float4* p = reinterpret_cast<const float4*>(in) + (size_t)i * 2;
  float4 a = p[0], b = p[1];
  bf16x8_s o;
  o.h[0] = __float2bfloat16(a.x); o.h[1] = __float2bfloat16(a.y);
  o.h[2] = __float2bfloat16(a.z); o.h[3] = __float2bfloat16(a.w);
  o.h[4] = __float2bfloat16(b.x); o.h[5] = __float2bfloat16(b.y);
  o.h[6] = __float2bfloat16(b.z); o.h[7] = __float2bfloat16(b.w);
  *reinterpret_cast<bf16x8_s*>(out + (size_t)i * 8) = o;
}

// ---------------- bf16 GEMM: C[M,N] = A[M,K] @ W[N,K]^T + bias -------------
// MODE 0: bf16 row-major [M][N]
// MODE 1: bf16 V-transpose epilogue: out[((b*16+h)*64+d)*2048 + t]
// MODE 2: fp32 row-major [M][N]
template <int MODE>
__global__ __launch_bounds__(256) void gemm_bt(
    const __hip_bfloat16* __restrict__ A, const __hip_bfloat16* __restrict__ W,
    const float* __restrict__ bias, void* __restrict__ Cout, int M, int N,
    int K) {
  constexpr int BM = 128, BN = 128, BK = 64;
  __shared__ __hip_bfloat16 As[BM][BK];
  __shared__ __hip_bfloat16 Ws[BN][BK];
  const int tid = threadIdx.x;
  const int lane = tid & 63;
  const int lrow = lane & 15;
  const int lhi = lane >> 4;
  const int lk8 = lhi * 8;
  const int wid = tid >> 6;
  const int wm = wid >> 1, wn = wid & 1;
  const int row0 = blockIdx.x * BM, col0 = blockIdx.y * BN;

  f32x4 acc[4][4] = {};

  for (int k0 = 0; k0 < K; k0 += BK) {
#pragma unroll
    for (int c = 0; c < 4; ++c) {
      const int e = (c * 256 + tid) * 8;           // this lane's elem offset
      const int eb = (c * 256 + (tid & 192)) * 8;  // wave-uniform LDS base
      const int r = e >> 6, cc = e & 63;
      __builtin_amdgcn_global_load_lds(
          (const __attribute__((address_space(1))) void*)(A + (size_t)(row0 + r) * K + k0 + cc),
          (__attribute__((address_space(3))) void*)(&As[0][0] + eb), 16, 0, 0);
    }
#pragma unroll
    for (int c = 0; c < 4; ++c) {
      const int e = (c * 256 + tid) * 8;
      const int eb = (c * 256 + (tid & 192)) * 8;
      const int r = e >> 6, cc = e & 63;
      __builtin_amdgcn_global_load_lds(
          (const __attribute__((address_space(1))) void*)(W + (size_t)(col0 + r) * K + k0 + cc),
          (__attribute__((address_space(3))) void*)(&Ws[0][0] + eb), 16, 0, 0);
    }
    __syncthreads();
#pragma unroll
    for (int kk = 0; kk < 2; ++kk) {
      bf16x8 af[4], bfr[4];
#pragma unroll
      for (int m = 0; m < 4; ++m)
        af[m] = *reinterpret_cast<const bf16x8*>(&As[wm * 64 + m * 16 + lrow][kk * 32 + lk8]);
#pragma unroll
      for (int n = 0; n < 4; ++n)
        bfr[n] = *reinterpret_cast<const bf16x8*>(&Ws[wn * 64 + n * 16 + lrow][kk * 32 + lk8]);
#pragma unroll
      for (int m = 0; m < 4; ++m)
#pragma unroll
        for (int n = 0; n < 4; ++n)
          acc[m][n] = __builtin_amdgcn_mfma_f32_16x16x32_bf16(af[m], bfr[n], acc[m][n], 0, 0, 0);
    }
    __syncthreads();
  }

  float bv[4];
#pragma unroll
  for (int n = 0; n < 4; ++n) bv[n] = bias[col0 + wn * 64 + n * 16 + lrow];

#pragma unroll
  for (int m = 0; m < 4; ++m) {
#pragma unroll
    for (int n = 0; n < 4; ++n) {
#pragma unroll
      for (int i = 0; i < 4; ++i) {
        const int row = row0 + wm * 64 + m * 16 + lhi * 4 + i;
        const int col = col0 + wn * 64 + n * 16 + lrow;
        const float v = acc[m][n][i] + bv[n];
        if constexpr (MODE == 0) {
          ((__hip_bfloat16*)Cout)[(size_t)row * N + col] = __float2bfloat16(v);
        } else if constexpr (MODE == 1) {
          const int t = row & 2047, b = row >> 11;
          const size_t idx =
              ((size_t)((b * 16 + (col >> 6)) * 64 + (col & 63))) * 2048 + t;
          ((__hip_bfloat16*)Cout)[idx] = __float2bfloat16(v);
        } else {
          ((float*)Cout)[(size_t)row * N + col] = v;
        }
      }
    }
  }
}

// ---------------- flash attention (swapped-QK^T, KVB=64) -------------------
// Q,K: [B*T][C] bf16 (head h at cols h*64..h*64+63). Vt: [B*H*64][T] bf16.
// Y: [B*T][C] bf16. Grid (B*H, T/64), 256 thr = 4 waves; wave owns 16 q-rows.
// S^T = mfma(K,Q): lane holds S[k = kv0+g*16+lhi*4+i][q = q0+lrow] -> the
// k-reduction is in-register (15 ops) + 2 shfl_xor, not 4-deep shfl chains.
__global__ __launch_bounds__(256) void attn_fwd(
    const __hip_bfloat16* __restrict__ Q, const __hip_bfloat16* __restrict__ Km,
    const __hip_bfloat16* __restrict__ Vt, __hip_bfloat16* __restrict__ Y) {
  constexpr int T = 2048, C = 1024, D = 64;
  const int tid = threadIdx.x;
  const int wid = tid >> 6;
  const int lane = tid & 63;
  const int lrow = lane & 15;
  const int lhi = lane >> 4;
  const int qt = (int)gridDim.y - 1 - (int)blockIdx.y;  // heavy blocks first
  const int bh = blockIdx.x;
  const int b = bh >> 4, h = bh & 15;
  const int q0 = qt * 64 + wid * 16;
  const int qrow = q0 + lrow;

  const __hip_bfloat16* Qb = Q + ((size_t)b * T) * C + h * D;
  const __hip_bfloat16* Kb = Km + ((size_t)b * T) * C + h * D;
  const __hip_bfloat16* Vb = Vt + (size_t)bh * D * T;

  __shared__ __hip_bfloat16 Plds[4][16][72];  // stride 72: 2-way-only conflicts

  bf16x8 qf[2];
#pragma unroll
  for (int kk = 0; kk < 2; ++kk)
    qf[kk] = *reinterpret_cast<const bf16x8*>(Qb + (size_t)qrow * C + kk * 32 + lhi * 8);

  f32x4 o[4] = {};
  float m = -1e30f, l = 0.f;  // state for q-row (q0 + lrow)

  const int kv_end = q0 + 16;
  for (int kv0 = 0; kv0 < kv_end; kv0 += 64) {
    // ---- S^T = K @ Q^T : 4 k-groups of 16, accumulate over d (2 halves)
    f32x4 s[4] = {};
#pragma unroll
    for (int g = 0; g < 4; ++g) {
#pragma unroll
      for (int kk = 0; kk < 2; ++kk) {
        bf16x8 kf = *reinterpret_cast<const bf16x8*>(
            Kb + (size_t)(kv0 + g * 16 + lrow) * C + kk * 32 + lhi * 8);
        s[g] = __builtin_amdgcn_mfma_f32_16x16x32_bf16(kf, qf[kk], s[g], 0, 0, 0);
      }
    }
    // ---- scale + causal mask + in-register row max
    float p[4][4];
    float mx = -1e30f;
#pragma unroll
    for (int g = 0; g < 4; ++g)
#pragma unroll
      for (int i = 0; i < 4; ++i) {
        const int k = kv0 + g * 16 + lhi * 4 + i;
        const float v = (k <= qrow) ? s[g][i] * 0.125f : -1e30f;
        p[g][i] = v;
        mx = fmaxf(mx, v);
      }
    mx = fmaxf(mx, __shfl_xor(mx, 16));
    mx = fmaxf(mx, __shfl_xor(mx, 32));
    const float nm = fmaxf(m, mx);
    const float alpha = __expf(m - nm);
    m = nm;
    float sum = 0.f;
#pragma unroll
    for (int g = 0; g < 4; ++g)
#pragma unroll
      for (int i = 0; i < 4; ++i) {
        p[g][i] = __expf(p[g][i] - nm);
        sum += p[g][i];
      }
    sum += __shfl_xor(sum, 16);
    sum += __shfl_xor(sum, 32);
    l = l * alpha + sum;
    // ---- broadcast alpha to O-fragment rows (row = 4*lhi+i) and rescale O
    float a4[4];
#pragma unroll
    for (int i = 0; i < 4; ++i) a4[i] = __shfl(alpha, 4 * lhi + i, 16);
#pragma unroll
    for (int f = 0; f < 4; ++f)
#pragma unroll
      for (int i = 0; i < 4; ++i) o[f][i] *= a4[i];
    // ---- P^T (per-lane rows) -> LDS as P[q][k], 8B writes
#pragma unroll
    for (int g = 0; g < 4; ++g) {
      bf16x4_s t;
#pragma unroll
      for (int i = 0; i < 4; ++i) t.h[i] = __float2bfloat16(p[g][i]);
      *reinterpret_cast<bf16x4_s*>(&Plds[wid][lrow][g * 16 + lhi * 4]) = t;
    }
    // ---- read P as A-fragments (q=lrow, k contiguous)
    bf16x8 pf[2];
#pragma unroll
    for (int n = 0; n < 2; ++n)
      pf[n] = *reinterpret_cast<const bf16x8*>(&Plds[wid][lrow][n * 32 + lhi * 8]);
    // ---- O += P V  (V^T rows are d -> contiguous 16B loads)
#pragma unroll
    for (int n = 0; n < 2; ++n)
#pragma unroll
      for (int f = 0; f < 4; ++f) {
        bf16x8 vf = *reinterpret_cast<const bf16x8*>(
            Vb + (size_t)(f * 16 + lrow) * T + kv0 + n * 32 + lhi * 8);
        o[f] = __builtin_amdgcn_mfma_f32_16x16x32_bf16(pf[n], vf, o[f], 0, 0, 0);
      }
  }
  // ---- normalize + store (broadcast l to O-fragment rows)
  float l4[4];
#pragma unroll
  for (int i = 0; i < 4; ++i) l4[i] = __shfl(l, 4 * lhi + i, 16);
#pragma unroll
  for (int f = 0; f < 4; ++f)
#pragma unroll
    for (int i = 0; i < 4; ++i) {
      const int row = q0 + 4 * lhi + i;
      Y[((size_t)b * T + row) * C + h * D + f * 16 + lrow] =
          __float2bfloat16(o[f][i] / l4[i]);
    }
}

// ---------------- host launch ----------------------------------------------
extern "C" void kernel_launch(void* const* d_in, const int* in_sizes, int n_in,
                              void* d_out, int out_size, void* d_ws,
                              size_t ws_size, hipStream_t stream) {
  const float* x = (const float*)d_in[0];
  const float* Wq = (const float*)d_in[1];
  const float* bq = (const float*)d_in[2];
  const float* Wk = (const float*)d_in[3];
  const float* bk = (const float*)d_in[4];
  const float* Wv = (const float*)d_in[5];
  const float* bv = (const float*)d_in[6];
  const float* Wp = (const float*)d_in[7];
  const float* bp = (const float*)d_in[8];
  float* out = (float*)d_out;

  __hip_bfloat16* ws = (__hip_bfloat16*)d_ws;
  __hip_bfloat16* xb = ws;                   // 8388608
  __hip_bfloat16* wqb = xb + 8388608;        // 1048576
  __hip_bfloat16* wkb = wqb + 1048576;
  __hip_bfloat16* wvb = wkb + 1048576;
  __hip_bfloat16* wpb = wvb + 1048576;
  __hip_bfloat16* Qs = wpb + 1048576;        // 8388608
  __hip_bfloat16* Ks = Qs + 8388608;
  __hip_bfloat16* Vts = Ks + 8388608;        // V^T: [B*H*64][2048]
  __hip_bfloat16* Ys = Vts + 8388608;        // attn out [B*T][C]
  // total = 92,274,688 bytes of d_ws

  cvt_kernel<<<4096, 256, 0, stream>>>(x, xb, 1048576);
  cvt_kernel<<<512, 256, 0, stream>>>(Wq, wqb, 131072);
  cvt_kernel<<<512, 256, 0, stream>>>(Wk, wkb, 131072);
  cvt_kernel<<<512, 256, 0, stream>>>(Wv, wvb, 131072);
  cvt_kernel<<<512, 256, 0, stream>>>(Wp, wpb, 131072);

  dim3 g(8192 / 128, 1024 / 128);
  gemm_bt<0><<<g, 256, 0, stream>>>(xb, wqb, bq, Qs, 8192, 1024, 1024);
  gemm_bt<0><<<g, 256, 0, stream>>>(xb, wkb, bk, Ks, 8192, 1024, 1024);
  gemm_bt<1><<<g, 256, 0, stream>>>(xb, wvb, bv, Vts, 8192, 1024, 1024);

  attn_fwd<<<dim3(64, 32), 256, 0, stream>>>(Qs, Ks, Vts, Ys);

  gemm_bt<2><<<g, 256, 0, stream>>>(Ys, wpb, bp, out, 8192, 1024, 1024);
}

// Round 3
// 266.761 us; speedup vs baseline: 2.2064x; 1.4374x over previous
//
#include <hip/hip_runtime.h>
#include <hip/hip_bf16.h>

typedef __attribute__((ext_vector_type(8))) short bf16x8;
typedef __attribute__((ext_vector_type(4))) float f32x4;

// ---------------- fp32 -> bf16 conversion (8 elems/thread) ----------------
struct bf16x8_s { __hip_bfloat16 h[8]; };
struct bf16x4_s { __hip_bfloat16 h[4]; };

__global__ void cvt_kernel(const float* __restrict__ in,
                           __hip_bfloat16* __restrict__ out, int n8) {
  int i = blockIdx.x * blockDim.x + threadIdx.x;
  if (i >= n8) return;
  const float4* p = reinterpret_cast<const float4*>(in) + (size_t)i * 2;
  float4 a = p[0], b = p[1];
  bf16x8_s o;
  o.h[0] = __float2bfloat16(a.x); o.h[1] = __float2bfloat16(a.y);
  o.h[2] = __float2bfloat16(a.z); o.h[3] = __float2bfloat16(a.w);
  o.h[4] = __float2bfloat16(b.x); o.h[5] = __float2bfloat16(b.y);
  o.h[6] = __float2bfloat16(b.z); o.h[7] = __float2bfloat16(b.w);
  *reinterpret_cast<bf16x8_s*>(out + (size_t)i * 8) = o;
}

// ---------------- bf16 GEMM: C[M,N] = A[M,K] @ W[N,K]^T + bias -------------
template <int MODE>
__global__ __launch_bounds__(256) void gemm_bt(
    const __hip_bfloat16* __restrict__ A, const __hip_bfloat16* __restrict__ W,
    const float* __restrict__ bias, void* __restrict__ Cout, int M, int N,
    int K) {
  constexpr int BM = 128, BN = 128, BK = 64;
  __shared__ __hip_bfloat16 As[BM][BK];
  __shared__ __hip_bfloat16 Ws[BN][BK];
  const int tid = threadIdx.x;
  const int lane = tid & 63;
  const int lrow = lane & 15;
  const int lhi = lane >> 4;
  const int lk8 = lhi * 8;
  const int wid = tid >> 6;
  const int wm = wid >> 1, wn = wid & 1;
  const int row0 = blockIdx.x * BM, col0 = blockIdx.y * BN;

  f32x4 acc[4][4] = {};

  for (int k0 = 0; k0 < K; k0 += BK) {
#pragma unroll
    for (int c = 0; c < 4; ++c) {
      const int e = (c * 256 + tid) * 8;
      const int eb = (c * 256 + (tid & 192)) * 8;
      const int r = e >> 6, cc = e & 63;
      __builtin_amdgcn_global_load_lds(
          (const __attribute__((address_space(1))) void*)(A + (size_t)(row0 + r) * K + k0 + cc),
          (__attribute__((address_space(3))) void*)(&As[0][0] + eb), 16, 0, 0);
    }
#pragma unroll
    for (int c = 0; c < 4; ++c) {
      const int e = (c * 256 + tid) * 8;
      const int eb = (c * 256 + (tid & 192)) * 8;
      const int r = e >> 6, cc = e & 63;
      __builtin_amdgcn_global_load_lds(
          (const __attribute__((address_space(1))) void*)(W + (size_t)(col0 + r) * K + k0 + cc),
          (__attribute__((address_space(3))) void*)(&Ws[0][0] + eb), 16, 0, 0);
    }
    __syncthreads();
#pragma unroll
    for (int kk = 0; kk < 2; ++kk) {
      bf16x8 af[4], bfr[4];
#pragma unroll
      for (int m = 0; m < 4; ++m)
        af[m] = *reinterpret_cast<const bf16x8*>(&As[wm * 64 + m * 16 + lrow][kk * 32 + lk8]);
#pragma unroll
      for (int n = 0; n < 4; ++n)
        bfr[n] = *reinterpret_cast<const bf16x8*>(&Ws[wn * 64 + n * 16 + lrow][kk * 32 + lk8]);
#pragma unroll
      for (int m = 0; m < 4; ++m)
#pragma unroll
        for (int n = 0; n < 4; ++n)
          acc[m][n] = __builtin_amdgcn_mfma_f32_16x16x32_bf16(af[m], bfr[n], acc[m][n], 0, 0, 0);
    }
    __syncthreads();
  }

  float bv[4];
#pragma unroll
  for (int n = 0; n < 4; ++n) bv[n] = bias[col0 + wn * 64 + n * 16 + lrow];

#pragma unroll
  for (int m = 0; m < 4; ++m) {
#pragma unroll
    for (int n = 0; n < 4; ++n) {
#pragma unroll
      for (int i = 0; i < 4; ++i) {
        const int row = row0 + wm * 64 + m * 16 + lhi * 4 + i;
        const int col = col0 + wn * 64 + n * 16 + lrow;
        const float v = acc[m][n][i] + bv[n];
        if constexpr (MODE == 0) {
          ((__hip_bfloat16*)Cout)[(size_t)row * N + col] = __float2bfloat16(v);
        } else if constexpr (MODE == 1) {
          const int t = row & 2047, b = row >> 11;
          const size_t idx =
              ((size_t)((b * 16 + (col >> 6)) * 64 + (col & 63))) * 2048 + t;
          ((__hip_bfloat16*)Cout)[idx] = __float2bfloat16(v);
        } else {
          ((float*)Cout)[(size_t)row * N + col] = v;
        }
      }
    }
  }
}

// ---------------- flash attention (swapped QK^T, 2 q-frags, KVB=64) --------
// Per-wave: 32 q-rows (2 fragments), online softmax in exp2 domain, T13
// defer-max, exactly one masked epilogue step (q-span 32 <= KVB 64).
template <bool MASKED>
__device__ __forceinline__ void attn_step(
    int kv0, int q0, int lrow, int lhi, const __hip_bfloat16* __restrict__ Kb,
    const __hip_bfloat16* __restrict__ Vb, const bf16x8 qf[2][2], f32x4 o[2][4],
    float m[2], float l[2], __hip_bfloat16* __restrict__ P) {
  constexpr float SC = 0.18033688011112042f;  // 0.125 * log2(e)
  constexpr float TH = 8.0f;
  // ---- S^T = K @ Q^T (kf shared across the two q-fragments)
  f32x4 s[2][4] = {};
#pragma unroll
  for (int g = 0; g < 4; ++g)
#pragma unroll
    for (int kk = 0; kk < 2; ++kk) {
      bf16x8 kf = *reinterpret_cast<const bf16x8*>(
          Kb + (size_t)(kv0 + g * 16 + lrow) * 1024 + kk * 32 + lhi * 8);
#pragma unroll
      for (int j = 0; j < 2; ++j)
        s[j][g] = __builtin_amdgcn_mfma_f32_16x16x32_bf16(kf, qf[j][kk], s[j][g], 0, 0, 0);
    }
  // ---- scale (exp2 domain) + optional mask + in-register row max
  float mx[2];
#pragma unroll
  for (int j = 0; j < 2; ++j) {
    float t = -1e30f;
#pragma unroll
    for (int g = 0; g < 4; ++g)
#pragma unroll
      for (int i = 0; i < 4; ++i) {
        float v = s[j][g][i] * SC;
        if (MASKED) {
          const int k = kv0 + g * 16 + lhi * 4 + i;
          if (k > q0 + j * 16 + lrow) v = -1e30f;
        }
        s[j][g][i] = v;
        t = fmaxf(t, v);
      }
    t = fmaxf(t, __shfl_xor(t, 16));
    t = fmaxf(t, __shfl_xor(t, 32));
    mx[j] = t;
  }
  // ---- T13 defer-max: only rescale when some row's max grew past m+TH
  const int need = (mx[0] > m[0] + TH) || (mx[1] > m[1] + TH);
  if (__any(need)) {
#pragma unroll
    for (int j = 0; j < 2; ++j) {
      const float nm = fmaxf(m[j], mx[j]);
      const float al = exp2f(m[j] - nm);
      m[j] = nm;
      l[j] *= al;
      float a4[4];
#pragma unroll
      for (int i = 0; i < 4; ++i) a4[i] = __shfl(al, 4 * lhi + i, 16);
#pragma unroll
      for (int f = 0; f < 4; ++f)
#pragma unroll
        for (int i = 0; i < 4; ++i) o[j][f][i] *= a4[i];
    }
  }
  // ---- P = exp2(s - m), row sums, write P[q][k] to LDS (stride 72)
#pragma unroll
  for (int j = 0; j < 2; ++j) {
    float sum = 0.f;
#pragma unroll
    for (int g = 0; g < 4; ++g) {
      bf16x4_s t4;
#pragma unroll
      for (int i = 0; i < 4; ++i) {
        const float p = exp2f(s[j][g][i] - m[j]);
        sum += p;
        t4.h[i] = __float2bfloat16(p);
      }
      *reinterpret_cast<bf16x4_s*>(P + (j * 16 + lrow) * 72 + g * 16 + lhi * 4) = t4;
    }
    sum += __shfl_xor(sum, 16);
    sum += __shfl_xor(sum, 32);
    l[j] += sum;
  }
  // ---- read P as A-fragments, O += P V (vf shared across fragments)
  bf16x8 pf[2][2];
#pragma unroll
  for (int j = 0; j < 2; ++j)
#pragma unroll
    for (int n = 0; n < 2; ++n)
      pf[j][n] = *reinterpret_cast<const bf16x8*>(P + (j * 16 + lrow) * 72 + n * 32 + lhi * 8);
#pragma unroll
  for (int n = 0; n < 2; ++n)
#pragma unroll
    for (int f = 0; f < 4; ++f) {
      bf16x8 vf = *reinterpret_cast<const bf16x8*>(
          Vb + (size_t)(f * 16 + lrow) * 2048 + kv0 + n * 32 + lhi * 8);
#pragma unroll
      for (int j = 0; j < 2; ++j)
        o[j][f] = __builtin_amdgcn_mfma_f32_16x16x32_bf16(pf[j][n], vf, o[j][f], 0, 0, 0);
    }
}

__global__ __launch_bounds__(256) void attn_fwd(
    const __hip_bfloat16* __restrict__ Q, const __hip_bfloat16* __restrict__ Km,
    const __hip_bfloat16* __restrict__ Vt, __hip_bfloat16* __restrict__ Y) {
  constexpr int T = 2048, C = 1024, D = 64;
  const int tid = threadIdx.x;
  const int wid = tid >> 6;
  const int lane = tid & 63;
  const int lrow = lane & 15;
  const int lhi = lane >> 4;
  // XCD-ownership swizzle: XCD (n&7) owns bh in [xcd*8, xcd*8+8) for the whole
  // kernel (K+V working set 8*512KB = 4MB = one XCD's L2). Heavy q-tiles first.
  const int n = blockIdx.x;
  const int xcd = n & 7;
  const int w = n >> 3;
  const int bh = xcd * 8 + (w & 7);
  const int qt = 15 - (w >> 3);
  const int b = bh >> 4, h = bh & 15;
  const int q0 = qt * 128 + wid * 32;

  const __hip_bfloat16* Qb = Q + ((size_t)b * T) * C + h * D;
  const __hip_bfloat16* Kb = Km + ((size_t)b * T) * C + h * D;
  const __hip_bfloat16* Vb = Vt + (size_t)bh * D * T;

  __shared__ __hip_bfloat16 Plds[4][2][16][72];
  __hip_bfloat16* P = &Plds[wid][0][0][0];

  bf16x8 qf[2][2];
#pragma unroll
  for (int j = 0; j < 2; ++j)
#pragma unroll
    for (int kk = 0; kk < 2; ++kk)
      qf[j][kk] = *reinterpret_cast<const bf16x8*>(
          Qb + (size_t)(q0 + j * 16 + lrow) * C + kk * 32 + lhi * 8);

  f32x4 o[2][4] = {};
  float m[2] = {-1e30f, -1e30f}, l[2] = {0.f, 0.f};

  // mask-free main loop: step fully unmasked iff kv0+63 <= q0
  const int full_end = ((q0 + 1) >> 6) << 6;
  for (int kv0 = 0; kv0 < full_end; kv0 += 64)
    attn_step<false>(kv0, q0, lrow, lhi, Kb, Vb, qf, o, m, l, P);
  attn_step<true>(full_end, q0, lrow, lhi, Kb, Vb, qf, o, m, l, P);

  // ---- normalize + store
#pragma unroll
  for (int j = 0; j < 2; ++j) {
    float l4[4];
#pragma unroll
    for (int i = 0; i < 4; ++i) l4[i] = __shfl(l[j], 4 * lhi + i, 16);
#pragma unroll
    for (int f = 0; f < 4; ++f)
#pragma unroll
      for (int i = 0; i < 4; ++i) {
        const int row = q0 + j * 16 + 4 * lhi + i;
        Y[((size_t)b * T + row) * C + h * D + f * 16 + lrow] =
            __float2bfloat16(o[j][f][i] / l4[i]);
      }
  }
}

// ---------------- host launch ----------------------------------------------
extern "C" void kernel_launch(void* const* d_in, const int* in_sizes, int n_in,
                              void* d_out, int out_size, void* d_ws,
                              size_t ws_size, hipStream_t stream) {
  const float* x = (const float*)d_in[0];
  const float* Wq = (const float*)d_in[1];
  const float* bq = (const float*)d_in[2];
  const float* Wk = (const float*)d_in[3];
  const float* bk = (const float*)d_in[4];
  const float* Wv = (const float*)d_in[5];
  const float* bv = (const float*)d_in[6];
  const float* Wp = (const float*)d_in[7];
  const float* bp = (const float*)d_in[8];
  float* out = (float*)d_out;

  __hip_bfloat16* ws = (__hip_bfloat16*)d_ws;
  __hip_bfloat16* xb = ws;                   // 8388608
  __hip_bfloat16* wqb = xb + 8388608;        // 1048576
  __hip_bfloat16* wkb = wqb + 1048576;
  __hip_bfloat16* wvb = wkb + 1048576;
  __hip_bfloat16* wpb = wvb + 1048576;
  __hip_bfloat16* Qs = wpb + 1048576;        // 8388608
  __hip_bfloat16* Ks = Qs + 8388608;
  __hip_bfloat16* Vts = Ks + 8388608;        // V^T: [B*H*64][2048]
  __hip_bfloat16* Ys = Vts + 8388608;        // attn out [B*T][C]

  cvt_kernel<<<4096, 256, 0, stream>>>(x, xb, 1048576);
  cvt_kernel<<<512, 256, 0, stream>>>(Wq, wqb, 131072);
  cvt_kernel<<<512, 256, 0, stream>>>(Wk, wkb, 131072);
  cvt_kernel<<<512, 256, 0, stream>>>(Wv, wvb, 131072);
  cvt_kernel<<<512, 256, 0, stream>>>(Wp, wpb, 131072);

  dim3 g(8192 / 128, 1024 / 128);
  gemm_bt<0><<<g, 256, 0, stream>>>(xb, wqb, bq, Qs, 8192, 1024, 1024);
  gemm_bt<0><<<g, 256, 0, stream>>>(xb, wkb, bk, Ks, 8192, 1024, 1024);
  gemm_bt<1><<<g, 256, 0, stream>>>(xb, wvb, bv, Vts, 8192, 1024, 1024);

  attn_fwd<<<dim3(1024), 256, 0, stream>>>(Qs, Ks, Vts, Ys);

  gemm_bt<2><<<g, 256, 0, stream>>>(Ys, wpb, bp, out, 8192, 1024, 1024);
}